// Round 8
// baseline (21790.921 us; speedup 1.0000x reference)
//
#include <hip/hip_runtime.h>
#include <math.h>

#define N_TOK 2048
#define DIM   512
#define K_TOP 50
#define NWG_LSTM 16

typedef short bf16x8 __attribute__((ext_vector_type(8)));
typedef float f32x4  __attribute__((ext_vector_type(4)));

// float -> bf16 (RNE)
static __device__ inline unsigned bfr(float x) {
  unsigned u = __float_as_uint(x);
  return (u + 0x7fffu + ((u >> 16) & 1u)) >> 16;
}

// ---------------- init: tag-packed h double-buffer + xcd exchange ----------------
__global__ __launch_bounds__(256) void init_kernel(unsigned long long* hbuf,
                                                   unsigned* xcdbuf) {
  int t = threadIdx.x;
  for (int k = t; k < 1024; k += 256) hbuf[k] = 0ull;   // tag 0, h=0.0f
  for (int k = t; k < NWG_LSTM*32; k += 256) xcdbuf[k] = 0u;
}

// ---------------- small fp32 GEMM (used only for Eproj, M=9) ----------------
__global__ __launch_bounds__(256) void gemm_nt(
    const float* __restrict__ A, int lda,
    const float* __restrict__ B, int ldb,
    float* __restrict__ C, int ldc,
    const float* __restrict__ bias1, const float* __restrict__ bias2,
    int M, int N, int K)
{
  __shared__ float As[16][64];
  __shared__ float Bs[16][64];
  const int tid = threadIdx.x;
  const int bm = blockIdx.y, bn = blockIdx.x;
  const int tx = tid & 15, ty = tid >> 4;
  const int lr = tid >> 2;
  const int lk = (tid & 3) << 2;
  const int arow = bm*64 + lr;
  const int brow = bn*64 + lr;
  float acc[4][4];
  #pragma unroll
  for (int a = 0; a < 4; ++a)
    #pragma unroll
    for (int b = 0; b < 4; ++b) acc[a][b] = 0.0f;

  for (int k0 = 0; k0 < K; k0 += 16) {
    float4 av = make_float4(0.f,0.f,0.f,0.f);
    float4 bv = make_float4(0.f,0.f,0.f,0.f);
    if (arow < M) av = *(const float4*)(A + (size_t)arow*lda + k0 + lk);
    if (brow < N) bv = *(const float4*)(B + (size_t)brow*ldb + k0 + lk);
    __syncthreads();
    As[lk+0][lr]=av.x; As[lk+1][lr]=av.y; As[lk+2][lr]=av.z; As[lk+3][lr]=av.w;
    Bs[lk+0][lr]=bv.x; Bs[lk+1][lr]=bv.y; Bs[lk+2][lr]=bv.z; Bs[lk+3][lr]=bv.w;
    __syncthreads();
    #pragma unroll
    for (int k = 0; k < 16; ++k) {
      float4 a4 = *(const float4*)(&As[k][ty<<2]);
      float4 b4 = *(const float4*)(&Bs[k][tx<<2]);
      float aa[4] = {a4.x,a4.y,a4.z,a4.w};
      float bb[4] = {b4.x,b4.y,b4.z,b4.w};
      #pragma unroll
      for (int ii = 0; ii < 4; ++ii)
        #pragma unroll
        for (int jj = 0; jj < 4; ++jj)
          acc[ii][jj] = fmaf(aa[ii], bb[jj], acc[ii][jj]);
    }
  }
  const int n0 = bn*64 + (tx<<2);
  float bc[4] = {0.f,0.f,0.f,0.f};
  if (bias1) {
    #pragma unroll
    for (int q = 0; q < 4; ++q) bc[q] += bias1[n0+q];
  }
  if (bias2) {
    #pragma unroll
    for (int q = 0; q < 4; ++q) bc[q] += bias2[n0+q];
  }
  #pragma unroll
  for (int ii = 0; ii < 4; ++ii) {
    int m = bm*64 + (ty<<2) + ii;
    if (m < M) {
      float4 o;
      o.x = acc[ii][0]+bc[0]; o.y = acc[ii][1]+bc[1];
      o.z = acc[ii][2]+bc[2]; o.w = acc[ii][3]+bc[3];
      *(float4*)(C + (size_t)m*ldc + n0) = o;
    }
  }
}

// ---------------- big fp32 GEMM: 128x128 tile, 8x8 acc, reg-prefetch staging ----
__global__ __launch_bounds__(256) void gemm_nt128(
    const float* __restrict__ A, int lda,
    const float* __restrict__ B, int ldb,
    float* __restrict__ C, int ldc,
    const float* __restrict__ bias1, const float* __restrict__ bias2,
    int K)
{
  __shared__ float As[16][128];
  __shared__ float Bs[16][128];
  const int tid = threadIdx.x;
  const int bm = blockIdx.y, bn = blockIdx.x;
  const int tx = tid & 15, ty = tid >> 4;
  const int sr = tid >> 1;
  const int sk = (tid & 1) << 3;

  const float* Ar = A + (size_t)(bm*128 + sr)*lda + sk;
  const float* Br = B + (size_t)(bn*128 + sr)*ldb + sk;

  float acc[8][8];
  #pragma unroll
  for (int r = 0; r < 8; ++r)
    #pragma unroll
    for (int c = 0; c < 8; ++c) acc[r][c] = 0.0f;

  float4 a0r = *(const float4*)(Ar + 0);
  float4 a1r = *(const float4*)(Ar + 4);
  float4 b0r = *(const float4*)(Br + 0);
  float4 b1r = *(const float4*)(Br + 4);
  {
    As[sk+0][sr]=a0r.x; As[sk+1][sr]=a0r.y; As[sk+2][sr]=a0r.z; As[sk+3][sr]=a0r.w;
    As[sk+4][sr]=a1r.x; As[sk+5][sr]=a1r.y; As[sk+6][sr]=a1r.z; As[sk+7][sr]=a1r.w;
    Bs[sk+0][sr]=b0r.x; Bs[sk+1][sr]=b0r.y; Bs[sk+2][sr]=b0r.z; Bs[sk+3][sr]=b0r.w;
    Bs[sk+4][sr]=b1r.x; Bs[sk+5][sr]=b1r.y; Bs[sk+6][sr]=b1r.z; Bs[sk+7][sr]=b1r.w;
  }
  __syncthreads();

  for (int k0 = 0; k0 < K; k0 += 16) {
    const bool more = (k0 + 16) < K;
    if (more) {
      a0r = *(const float4*)(Ar + k0+16);
      a1r = *(const float4*)(Ar + k0+20);
      b0r = *(const float4*)(Br + k0+16);
      b1r = *(const float4*)(Br + k0+20);
    }
    #pragma unroll
    for (int k = 0; k < 16; ++k) {
      float4 a0 = *(const float4*)(&As[k][ty<<3]);
      float4 a1 = *(const float4*)(&As[k][(ty<<3)+4]);
      float4 b0 = *(const float4*)(&Bs[k][tx<<3]);
      float4 b1 = *(const float4*)(&Bs[k][(tx<<3)+4]);
      float aa[8] = {a0.x,a0.y,a0.z,a0.w,a1.x,a1.y,a1.z,a1.w};
      float bb[8] = {b0.x,b0.y,b0.z,b0.w,b1.x,b1.y,b1.z,b1.w};
      #pragma unroll
      for (int r = 0; r < 8; ++r)
        #pragma unroll
        for (int c = 0; c < 8; ++c)
          acc[r][c] = fmaf(aa[r], bb[c], acc[r][c]);
    }
    if (more) {
      __syncthreads();
      As[sk+0][sr]=a0r.x; As[sk+1][sr]=a0r.y; As[sk+2][sr]=a0r.z; As[sk+3][sr]=a0r.w;
      As[sk+4][sr]=a1r.x; As[sk+5][sr]=a1r.y; As[sk+6][sr]=a1r.z; As[sk+7][sr]=a1r.w;
      Bs[sk+0][sr]=b0r.x; Bs[sk+1][sr]=b0r.y; Bs[sk+2][sr]=b0r.z; Bs[sk+3][sr]=b0r.w;
      Bs[sk+4][sr]=b1r.x; Bs[sk+5][sr]=b1r.y; Bs[sk+6][sr]=b1r.z; Bs[sk+7][sr]=b1r.w;
      __syncthreads();
    }
  }

  const int n0 = bn*128 + (tx<<3);
  float bc[8] = {0,0,0,0,0,0,0,0};
  if (bias1) {
    #pragma unroll
    for (int c = 0; c < 8; ++c) bc[c] += bias1[n0+c];
  }
  if (bias2) {
    #pragma unroll
    for (int c = 0; c < 8; ++c) bc[c] += bias2[n0+c];
  }
  #pragma unroll
  for (int r = 0; r < 8; ++r) {
    int m = bm*128 + (ty<<3) + r;
    float4 o0, o1;
    o0.x=acc[r][0]+bc[0]; o0.y=acc[r][1]+bc[1]; o0.z=acc[r][2]+bc[2]; o0.w=acc[r][3]+bc[3];
    o1.x=acc[r][4]+bc[4]; o1.y=acc[r][5]+bc[5]; o1.z=acc[r][6]+bc[6]; o1.w=acc[r][7]+bc[7];
    *(float4*)(C + (size_t)m*ldc + n0)     = o0;
    *(float4*)(C + (size_t)m*ldc + n0 + 4) = o1;
  }
}

// ---------------- LSTM recurrence v6: L2-local sync when colocated ----------------
// Workers = bid%8==0 (dispatch heuristic puts them on one XCD — R7 FETCH evidence).
// Ground truth via HW_REG_XCC_ID exchange; fast path (sc0-only L2 ops) enabled
// only when ALL workers share an XCD. Producer dual-stores (sc0 + agent) and the
// poll escalates to agent loads every 64 spins, so every cache-semantics case
// still terminates correctly.
__global__ __launch_bounds__(512, 2) void lstm_kernel(
    const float* __restrict__ W_hh,   // [2048,512]
    const float* __restrict__ xp,     // [2048][2048]
    float* __restrict__ words,        // [2048][512]
    unsigned long long* __restrict__ hbuf,  // [2][512] packed (seq<<32|bits)
    unsigned* __restrict__ xcdbuf)    // [16*32]
{
  if (blockIdx.x & 7) return;
  const int wg  = blockIdx.x >> 3;    // role 0..15
  const int tid = threadIdx.x;
  const int row_l = tid >> 2;         // 0..127
  const int q     = tid & 3;          // k-quarter
  const int g  = row_l >> 5;          // 0..3 (i,f,g,o)
  const int cl = row_l & 31;
  const int cell = (wg<<5) + cl;      // 0..511
  const int grow = (g<<9) + cell;     // global gate row

  float4 wv[32];
  {
    const float4* wp = (const float4*)(W_hh + (size_t)grow*512 + (q<<7));
    #pragma unroll
    for (int k = 0; k < 32; ++k) wv[k] = wp[k];
  }

  // ---- one-time XCD colocation detection (ground truth, not heuristic) ----
  __shared__ int same_sh;
  {
    unsigned myxcc;
    asm volatile("s_getreg_b32 %0, hwreg(HW_REG_XCC_ID)" : "=s"(myxcc));
    if (tid == 0) {
      __hip_atomic_store(xcdbuf + wg*32, myxcc + 1u,
                         __ATOMIC_RELAXED, __HIP_MEMORY_SCOPE_AGENT);
      int same = 1;
      for (int k = 0; k < NWG_LSTM; ++k) {
        unsigned v;
        do {
          v = __hip_atomic_load(xcdbuf + k*32, __ATOMIC_RELAXED, __HIP_MEMORY_SCOPE_AGENT);
        } while (v == 0u);
        same &= (v == myxcc + 1u);
      }
      same_sh = same;
    }
  }
  __syncthreads();
  const bool fast = (same_sh != 0);

  __shared__ float h_lds[2][4*132];   // parity double-buffer, q-blocks padded
  __shared__ float gates_lds[128];
  float c_state = 0.0f;

  for (int t = 0; t < N_TOK; ++t) {
    float xg = xp[(size_t)t*2048 + grow];   // prefetch (poll-independent)

    // poll own packed datum: tag==t means h(t)[tid] has arrived
    {
      const unsigned long long* src = hbuf + ((t & 1) << 9) + tid;
      unsigned long long v;
      if (fast) {
        int spin = 0;
        for (;;) {
          asm volatile("global_load_dwordx2 %0, %1, off sc0\n\ts_waitcnt vmcnt(0)"
                       : "=&v"(v) : "v"(src) : "memory");
          if ((unsigned)(v >> 32) == (unsigned)t) break;
          if ((++spin & 63) == 0) {
            v = __hip_atomic_load(src, __ATOMIC_RELAXED, __HIP_MEMORY_SCOPE_AGENT);
            if ((unsigned)(v >> 32) == (unsigned)t) break;
          }
        }
      } else {
        do {
          v = __hip_atomic_load(src, __ATOMIC_RELAXED, __HIP_MEMORY_SCOPE_AGENT);
        } while ((unsigned)(v >> 32) != (unsigned)t);
      }
      h_lds[t & 1][(tid >> 7)*132 + (tid & 127)] = __uint_as_float((unsigned)v);
    }
    __syncthreads();                        // barrier 1

    const float4* hv4 = (const float4*)(h_lds[t & 1] + q*132);
    float a0=0.f,a1=0.f,a2=0.f,a3=0.f;
    #pragma unroll
    for (int k = 0; k < 32; ++k) {
      float4 hv = hv4[k];
      a0 = fmaf(wv[k].x, hv.x, a0);
      a1 = fmaf(wv[k].y, hv.y, a1);
      a2 = fmaf(wv[k].z, hv.z, a2);
      a3 = fmaf(wv[k].w, hv.w, a3);
    }
    float acc = (a0+a1)+(a2+a3);
    acc += __shfl_xor(acc, 1);
    acc += __shfl_xor(acc, 2);        // all 4 q-lanes hold the full row sum
    if (q == 0) {
      float gate = acc + xg;
      gates_lds[row_l] = (g == 2) ? tanhf(gate) : 1.0f/(1.0f + expf(-gate));
    }
    __syncthreads();                        // barrier 2
    if (tid < 32) {
      float iv = gates_lds[tid];
      float fv = gates_lds[32+tid];
      float gv = gates_lds[64+tid];
      float ov = gates_lds[96+tid];
      c_state = fmaf(fv, c_state, iv*gv);
      float h = ov * tanhf(c_state);
      unsigned long long pv =
          ((unsigned long long)(unsigned)(t+1) << 32) |
          (unsigned long long)__float_as_uint(h);
      unsigned long long* dst = hbuf + (((t+1) & 1) << 9) + (wg<<5) + tid;
      if (fast) {
        // L2-local publish (critical path), then agent mirror (safety net for
        // any consumer whose sc0 path misses — keeps all cases terminating).
        asm volatile("global_store_dwordx2 %0, %1, off sc0"
                     :: "v"(dst), "v"(pv) : "memory");
        __hip_atomic_store(dst, pv, __ATOMIC_RELAXED, __HIP_MEMORY_SCOPE_AGENT);
      } else {
        __hip_atomic_store(dst, pv, __ATOMIC_RELAXED, __HIP_MEMORY_SCOPE_AGENT);
      }
      words[(size_t)t*512 + (wg<<5) + tid] = h;   // after publish: off critical path
    }
    // no 3rd barrier (parity argument, see R7)
  }
}

// ---------------- top-50 per row (strict lower triangle), jax top_k tie semantics ----------------
__global__ __launch_bounds__(256) void topk_kernel(
    const float* __restrict__ rough,  // [2048][2048]
    float* __restrict__ tsc,          // [2048][50]
    int* __restrict__ tidx)           // [2048][50]
{
  const int i = blockIdx.x;
  const int tid = threadIdx.x;
  float v[8];
  #pragma unroll
  for (int s = 0; s < 8; ++s) {
    int j = (s<<8) + tid;
    v[s] = (j < i) ? rough[(size_t)i*N_TOK + j] : -__builtin_inff();
  }
  __shared__ float rv[4];
  __shared__ int   ri[4];
  __shared__ int   wsh;
  for (int p = 0; p < K_TOP; ++p) {
    if (p >= i) {   // padding: idx=p, finite sentinel score
      if (tid == 0) { tsc[i*K_TOP+p] = -1.0e30f; tidx[i*K_TOP+p] = p; }
      continue;
    }
    float m = -__builtin_inff(); int mi = 0x7fffffff;
    #pragma unroll
    for (int s = 0; s < 8; ++s) {
      int j = (s<<8) + tid;
      bool b = (v[s] > m);
      m = b ? v[s] : m; mi = b ? j : mi;
    }
    #pragma unroll
    for (int off = 32; off > 0; off >>= 1) {
      float m2 = __shfl_xor(m, off);
      int   i2 = __shfl_xor(mi, off);
      bool b = (m2 > m) || (m2 == m && i2 < mi);
      m = b ? m2 : m; mi = b ? i2 : mi;
    }
    if ((tid & 63) == 0) { rv[tid>>6] = m; ri[tid>>6] = mi; }
    __syncthreads();
    if (tid == 0) {
      #pragma unroll
      for (int wv = 1; wv < 4; ++wv) {
        bool b = (rv[wv] > m) || (rv[wv] == m && ri[wv] < mi);
        m = b ? rv[wv] : m; mi = b ? ri[wv] : mi;
      }
      tsc[i*K_TOP+p] = m;
      tidx[i*K_TOP+p] = mi;
      wsh = mi;
    }
    __syncthreads();
    const int widx = wsh;
    if ((widx & 255) == tid) {
      #pragma unroll
      for (int s = 0; s < 8; ++s) if ((widx >> 8) == s) v[s] = -__builtin_inff();
    }
  }
}

// ---------------- Wc -> bf16 fragment-packed layout ----------------
__global__ __launch_bounds__(256) void pack_wc(const float* __restrict__ hid_W,
                                               bf16x8* __restrict__ WcB) {
  int id = blockIdx.x*256 + threadIdx.x;   // 32768
  int c  = id & 15;
  int lg = (id >> 4) & 3;
  int ks = (id >> 6) & 15;
  int nt = id >> 10;
  const float* src = hid_W + (size_t)(nt*16 + c)*1600 + 1024 + ks*32 + lg*8;
  bf16x8 v;
  #pragma unroll
  for (int e = 0; e < 8; ++e) v[e] = (short)bfr(src[e]);
  WcB[id] = v;
}

// ---------------- pair FFNN v2: bf16 MFMA, per-i block ----------------
__global__ __launch_bounds__(256) void pair_kernel(
    const float* __restrict__ words,
    const bf16x8* __restrict__ WcB,
    const float* __restrict__ Aproj,    // [2048][512] (includes hid_b)
    const float* __restrict__ Bproj,    // [2048][512]
    const float* __restrict__ Eproj,    // [9][512]
    const float* __restrict__ outW,     // [512]
    const float* __restrict__ out_b,    // [1]
    const float* __restrict__ tsc,
    const int* __restrict__ tidx,
    float* __restrict__ out)            // [2048][51]
{
  __shared__ unsigned m_lds[64*256];    // 64 rows x 512 bf16 (64 KB)
  __shared__ int   j_sm[K_TOP];
  __shared__ int   d_sm[K_TOP];
  __shared__ float s_sm[K_TOP];
  const int i = blockIdx.x;
  const int tid = threadIdx.x;

  if (tid < K_TOP) {
    int j = tidx[i*K_TOP + tid];
    int dist = i - j; if (dist < 1) dist = 1;
    int didx;
    if (dist < 5) didx = dist - 1;
    else { int l = 31 - __clz(dist); if (l > 6) l = 6; didx = l + 2; }
    j_sm[tid] = j; d_sm[tid] = didx;
    s_sm[tid] = tsc[i*K_TOP + tid];
  }
  __syncthreads();

  {
    const int k4 = tid & 127;
    const int r0 = tid >> 7;
    const int kb = k4 >> 1, half = k4 & 1;
    const float4 a4 = *(const float4*)(words + (size_t)i*DIM + (k4<<2));
    for (int r = r0; r < K_TOP; r += 2) {
      const float4 w4 = *(const float4*)(words + (size_t)j_sm[r]*DIM + (k4<<2));
      unsigned lo = bfr(a4.x*w4.x) | (bfr(a4.y*w4.y) << 16);
      unsigned hi = bfr(a4.z*w4.z) | (bfr(a4.w*w4.w) << 16);
      unsigned off = (unsigned)r*256 + (unsigned)((kb ^ (r&7))<<2) + (half<<1);
      m_lds[off]   = lo;
      m_lds[off+1] = hi;
    }
    for (int r = K_TOP + r0; r < 64; r += 2) {
      unsigned off = (unsigned)r*256 + (unsigned)((kb ^ (r&7))<<2) + (half<<1);
      m_lds[off] = 0u; m_lds[off+1] = 0u;
    }
  }
  __syncthreads();

  const int w    = tid >> 6;
  const int lane = tid & 63;
  const int c    = lane & 15;
  const int lg   = lane >> 4;
  const int row  = (w << 4) + c;

  f32x4 acc[32];
  #pragma unroll
  for (int nt = 0; nt < 32; ++nt) acc[nt] = (f32x4){0.f,0.f,0.f,0.f};

  for (int ks = 0; ks < 16; ++ks) {
    const int kb = (ks << 2) + lg;
    bf16x8 a = *(const bf16x8*)(m_lds + (unsigned)row*256 + (unsigned)((kb ^ (row&7))<<2));
    const bf16x8* wbp = WcB + ((ks << 6) + (lg << 4) + c);
    #pragma unroll
    for (int nt = 0; nt < 32; ++nt) {
      bf16x8 b = wbp[nt << 10];
      acc[nt] = __builtin_amdgcn_mfma_f32_16x16x32_bf16(a, b, acc[nt], 0, 0, 0);
    }
  }

  const float ob = out_b[0];
  const int srow0 = (w << 4) + (lg << 2);
  const float* bpr[4];
  const float* epr[4];
  #pragma unroll
  for (int reg = 0; reg < 4; ++reg) {
    int srow = srow0 + reg;
    int jr = (srow < K_TOP) ? j_sm[srow] : 0;
    int dr = (srow < K_TOP) ? d_sm[srow] : 0;
    bpr[reg] = Bproj + (size_t)jr*DIM;
    epr[reg] = Eproj + (size_t)dr*DIM;
  }
  float p[4] = {0.f,0.f,0.f,0.f};
  #pragma unroll
  for (int nt = 0; nt < 32; ++nt) {
    int col = (nt << 4) + c;
    float ap = Aproj[(size_t)i*DIM + col];
    float ow = outW[col];
    #pragma unroll
    for (int reg = 0; reg < 4; ++reg) {
      float v = acc[nt][reg] + ap + bpr[reg][col] + epr[reg][col];
      v = (v >= 0.f) ? v : 0.01f*v;
      p[reg] = fmaf(v, ow, p[reg]);
    }
  }
  #pragma unroll
  for (int reg = 0; reg < 4; ++reg) {
    #pragma unroll
    for (int off = 1; off < 16; off <<= 1) p[reg] += __shfl_xor(p[reg], off);
  }
  if (c == 0) {
    #pragma unroll
    for (int reg = 0; reg < 4; ++reg) {
      int srow = srow0 + reg;
      if (srow < K_TOP) out[(size_t)i*51 + 1 + srow] = s_sm[srow] + p[reg] + ob;
    }
  }
  if (tid == 0) out[(size_t)i*51] = 1e-7f;
}

// ---------------- host ----------------
extern "C" void kernel_launch(void* const* d_in, const int* in_sizes, int n_in,
                              void* d_out, int out_size, void* d_ws, size_t ws_size,
                              hipStream_t stream) {
  const float* wf       = (const float*)d_in[0];
  const float* W_ih     = (const float*)d_in[1];
  const float* W_hh     = (const float*)d_in[2];
  const float* b_ih     = (const float*)d_in[3];
  const float* b_hh     = (const float*)d_in[4];
  const float* bil_W    = (const float*)d_in[5];
  const float* bil_b    = (const float*)d_in[6];
  const float* dist_emb = (const float*)d_in[7];
  const float* hid_W    = (const float*)d_in[8];
  const float* hid_b    = (const float*)d_in[9];
  const float* out_W    = (const float*)d_in[10];
  const float* out_b    = (const float*)d_in[11];
  (void)in_sizes; (void)n_in; (void)out_size; (void)ws_size;

  float* ws    = (float*)d_ws;
  float* xp    = ws;                        // 4M floats; reused as `rough`
  float* rough = ws;
  float* words = ws + 4*1024*1024;
  float* tmp   = words + N_TOK*DIM;
  float* Aproj = tmp   + N_TOK*DIM;
  float* Bproj = Aproj + N_TOK*DIM;
  float* Eproj = Bproj + N_TOK*DIM;
  bf16x8* WcB  = (bf16x8*)(Eproj + 8192);   // 512 KB
  float* tsc   = Eproj + 8192 + 131072;
  unsigned long long* hbuf = (unsigned long long*)(tsc + 102400);
  unsigned* xcdbuf = (unsigned*)(hbuf + 1024);

  float* out_f  = (float*)d_out;
  int*   idx_out = (int*)(out_f + N_TOK*(K_TOP+1));

  dim3 blk(256);
  init_kernel<<<1, blk, 0, stream>>>(hbuf, xcdbuf);
  // xp = wf @ W_ih^T + b_ih + b_hh      [2048 x 2048 x 512]
  gemm_nt128<<<dim3(16,16), blk, 0, stream>>>(wf, DIM, W_ih, DIM, xp, 2048,
                                              b_ih, b_hh, DIM);
  lstm_kernel<<<NWG_LSTM*8, 512, 0, stream>>>(W_hh, xp, words, hbuf, xcdbuf);
  // tmp = words @ bil_W^T + bil_b       [2048 x 512 x 512]
  gemm_nt128<<<dim3(4,16), blk, 0, stream>>>(words, DIM, bil_W, DIM, tmp, DIM,
                                             bil_b, nullptr, DIM);
  // rough = tmp @ words^T               [2048 x 2048 x 512]
  gemm_nt128<<<dim3(16,16), blk, 0, stream>>>(tmp, DIM, words, DIM, rough, 2048,
                                              nullptr, nullptr, DIM);
  // projections of hid_W blocks         [2048 x 512 x 512]
  gemm_nt128<<<dim3(4,16), blk, 0, stream>>>(words, DIM, hid_W,       1600, Aproj, DIM,
                                             hid_b, nullptr, DIM);
  gemm_nt128<<<dim3(4,16), blk, 0, stream>>>(words, DIM, hid_W + 512, 1600, Bproj, DIM,
                                             nullptr, nullptr, DIM);
  gemm_nt<<<dim3(8,1), blk, 0, stream>>>(dist_emb, 64, hid_W + 1536, 1600, Eproj, DIM,
                                         nullptr, nullptr, 9, DIM, 64);
  pack_wc<<<128, blk, 0, stream>>>(hid_W, WcB);
  topk_kernel<<<N_TOK, blk, 0, stream>>>(rough, tsc, idx_out);
  pair_kernel<<<N_TOK, blk, 0, stream>>>(words, WcB, Aproj, Bproj, Eproj,
                                         out_W, out_b, tsc, idx_out, out_f);
}

// Round 9
// 3644.056 us; speedup vs baseline: 5.9799x; 5.9799x over previous
//
#include <hip/hip_runtime.h>
#include <math.h>

#define N_TOK 2048
#define DIM   512
#define K_TOP 50
#define NWG_LSTM 16

typedef short bf16x8 __attribute__((ext_vector_type(8)));
typedef float f32x4  __attribute__((ext_vector_type(4)));

// float -> bf16 (RNE)
static __device__ inline unsigned bfr(float x) {
  unsigned u = __float_as_uint(x);
  return (u + 0x7fffu + ((u >> 16) & 1u)) >> 16;
}

// ---------------- init: tag-packed h double-buffer ----------------
__global__ __launch_bounds__(256) void init_kernel(unsigned long long* hbuf) {
  int t = threadIdx.x;
  for (int k = t; k < 1024; k += 256) hbuf[k] = 0ull;   // tag 0, h=0.0f
}

// ---------------- small fp32 GEMM (used only for Eproj, M=9) ----------------
__global__ __launch_bounds__(256) void gemm_nt(
    const float* __restrict__ A, int lda,
    const float* __restrict__ B, int ldb,
    float* __restrict__ C, int ldc,
    const float* __restrict__ bias1, const float* __restrict__ bias2,
    int M, int N, int K)
{
  __shared__ float As[16][64];
  __shared__ float Bs[16][64];
  const int tid = threadIdx.x;
  const int bm = blockIdx.y, bn = blockIdx.x;
  const int tx = tid & 15, ty = tid >> 4;
  const int lr = tid >> 2;
  const int lk = (tid & 3) << 2;
  const int arow = bm*64 + lr;
  const int brow = bn*64 + lr;
  float acc[4][4];
  #pragma unroll
  for (int a = 0; a < 4; ++a)
    #pragma unroll
    for (int b = 0; b < 4; ++b) acc[a][b] = 0.0f;

  for (int k0 = 0; k0 < K; k0 += 16) {
    float4 av = make_float4(0.f,0.f,0.f,0.f);
    float4 bv = make_float4(0.f,0.f,0.f,0.f);
    if (arow < M) av = *(const float4*)(A + (size_t)arow*lda + k0 + lk);
    if (brow < N) bv = *(const float4*)(B + (size_t)brow*ldb + k0 + lk);
    __syncthreads();
    As[lk+0][lr]=av.x; As[lk+1][lr]=av.y; As[lk+2][lr]=av.z; As[lk+3][lr]=av.w;
    Bs[lk+0][lr]=bv.x; Bs[lk+1][lr]=bv.y; Bs[lk+2][lr]=bv.z; Bs[lk+3][lr]=bv.w;
    __syncthreads();
    #pragma unroll
    for (int k = 0; k < 16; ++k) {
      float4 a4 = *(const float4*)(&As[k][ty<<2]);
      float4 b4 = *(const float4*)(&Bs[k][tx<<2]);
      float aa[4] = {a4.x,a4.y,a4.z,a4.w};
      float bb[4] = {b4.x,b4.y,b4.z,b4.w};
      #pragma unroll
      for (int ii = 0; ii < 4; ++ii)
        #pragma unroll
        for (int jj = 0; jj < 4; ++jj)
          acc[ii][jj] = fmaf(aa[ii], bb[jj], acc[ii][jj]);
    }
  }
  const int n0 = bn*64 + (tx<<2);
  float bc[4] = {0.f,0.f,0.f,0.f};
  if (bias1) {
    #pragma unroll
    for (int q = 0; q < 4; ++q) bc[q] += bias1[n0+q];
  }
  if (bias2) {
    #pragma unroll
    for (int q = 0; q < 4; ++q) bc[q] += bias2[n0+q];
  }
  #pragma unroll
  for (int ii = 0; ii < 4; ++ii) {
    int m = bm*64 + (ty<<2) + ii;
    if (m < M) {
      float4 o;
      o.x = acc[ii][0]+bc[0]; o.y = acc[ii][1]+bc[1];
      o.z = acc[ii][2]+bc[2]; o.w = acc[ii][3]+bc[3];
      *(float4*)(C + (size_t)m*ldc + n0) = o;
    }
  }
}

// ---------------- big fp32 GEMM: 128x128 tile, 8x8 acc, reg-prefetch staging ----
__global__ __launch_bounds__(256) void gemm_nt128(
    const float* __restrict__ A, int lda,
    const float* __restrict__ B, int ldb,
    float* __restrict__ C, int ldc,
    const float* __restrict__ bias1, const float* __restrict__ bias2,
    int K)
{
  __shared__ float As[16][128];
  __shared__ float Bs[16][128];
  const int tid = threadIdx.x;
  const int bm = blockIdx.y, bn = blockIdx.x;
  const int tx = tid & 15, ty = tid >> 4;
  const int sr = tid >> 1;
  const int sk = (tid & 1) << 3;

  const float* Ar = A + (size_t)(bm*128 + sr)*lda + sk;
  const float* Br = B + (size_t)(bn*128 + sr)*ldb + sk;

  float acc[8][8];
  #pragma unroll
  for (int r = 0; r < 8; ++r)
    #pragma unroll
    for (int c = 0; c < 8; ++c) acc[r][c] = 0.0f;

  float4 a0r = *(const float4*)(Ar + 0);
  float4 a1r = *(const float4*)(Ar + 4);
  float4 b0r = *(const float4*)(Br + 0);
  float4 b1r = *(const float4*)(Br + 4);
  {
    As[sk+0][sr]=a0r.x; As[sk+1][sr]=a0r.y; As[sk+2][sr]=a0r.z; As[sk+3][sr]=a0r.w;
    As[sk+4][sr]=a1r.x; As[sk+5][sr]=a1r.y; As[sk+6][sr]=a1r.z; As[sk+7][sr]=a1r.w;
    Bs[sk+0][sr]=b0r.x; Bs[sk+1][sr]=b0r.y; Bs[sk+2][sr]=b0r.z; Bs[sk+3][sr]=b0r.w;
    Bs[sk+4][sr]=b1r.x; Bs[sk+5][sr]=b1r.y; Bs[sk+6][sr]=b1r.z; Bs[sk+7][sr]=b1r.w;
  }
  __syncthreads();

  for (int k0 = 0; k0 < K; k0 += 16) {
    const bool more = (k0 + 16) < K;
    if (more) {
      a0r = *(const float4*)(Ar + k0+16);
      a1r = *(const float4*)(Ar + k0+20);
      b0r = *(const float4*)(Br + k0+16);
      b1r = *(const float4*)(Br + k0+20);
    }
    #pragma unroll
    for (int k = 0; k < 16; ++k) {
      float4 a0 = *(const float4*)(&As[k][ty<<3]);
      float4 a1 = *(const float4*)(&As[k][(ty<<3)+4]);
      float4 b0 = *(const float4*)(&Bs[k][tx<<3]);
      float4 b1 = *(const float4*)(&Bs[k][(tx<<3)+4]);
      float aa[8] = {a0.x,a0.y,a0.z,a0.w,a1.x,a1.y,a1.z,a1.w};
      float bb[8] = {b0.x,b0.y,b0.z,b0.w,b1.x,b1.y,b1.z,b1.w};
      #pragma unroll
      for (int r = 0; r < 8; ++r)
        #pragma unroll
        for (int c = 0; c < 8; ++c)
          acc[r][c] = fmaf(aa[r], bb[c], acc[r][c]);
    }
    if (more) {
      __syncthreads();
      As[sk+0][sr]=a0r.x; As[sk+1][sr]=a0r.y; As[sk+2][sr]=a0r.z; As[sk+3][sr]=a0r.w;
      As[sk+4][sr]=a1r.x; As[sk+5][sr]=a1r.y; As[sk+6][sr]=a1r.z; As[sk+7][sr]=a1r.w;
      Bs[sk+0][sr]=b0r.x; Bs[sk+1][sr]=b0r.y; Bs[sk+2][sr]=b0r.z; Bs[sk+3][sr]=b0r.w;
      Bs[sk+4][sr]=b1r.x; Bs[sk+5][sr]=b1r.y; Bs[sk+6][sr]=b1r.z; Bs[sk+7][sr]=b1r.w;
      __syncthreads();
    }
  }

  const int n0 = bn*128 + (tx<<3);
  float bc[8] = {0,0,0,0,0,0,0,0};
  if (bias1) {
    #pragma unroll
    for (int c = 0; c < 8; ++c) bc[c] += bias1[n0+c];
  }
  if (bias2) {
    #pragma unroll
    for (int c = 0; c < 8; ++c) bc[c] += bias2[n0+c];
  }
  #pragma unroll
  for (int r = 0; r < 8; ++r) {
    int m = bm*128 + (ty<<3) + r;
    float4 o0, o1;
    o0.x=acc[r][0]+bc[0]; o0.y=acc[r][1]+bc[1]; o0.z=acc[r][2]+bc[2]; o0.w=acc[r][3]+bc[3];
    o1.x=acc[r][4]+bc[4]; o1.y=acc[r][5]+bc[5]; o1.z=acc[r][6]+bc[6]; o1.w=acc[r][7]+bc[7];
    *(float4*)(C + (size_t)m*ldc + n0)     = o0;
    *(float4*)(C + (size_t)m*ldc + n0 + 4) = o1;
  }
}

// ---------------- LSTM recurrence v7 (= R7 v5, sc0 experiment reverted) ----------------
// Agent-scope tag-fused publish/poll (sc1 path to MALL) is the proven-fastest
// sync: 1.75 us/step. sc0 "L2-local" sync FAILED (R8: sc0 ops lack cross-CU
// visibility on gfx950 — stale L1 until the sc1-path op; 6x regression).
// XCD-colocation dispatch (bid%8==0) kept: it halves FETCH (shared W/xp in one
// L2, R7 evidence) even though it cannot shortcut sync latency.
__global__ __launch_bounds__(512, 2) void lstm_kernel(
    const float* __restrict__ W_hh,   // [2048,512]
    const float* __restrict__ xp,     // [2048][2048]
    float* __restrict__ words,        // [2048][512]
    unsigned long long* __restrict__ hbuf)  // [2][512] packed (seq<<32|bits)
{
  if (blockIdx.x & 7) return;
  const int wg  = blockIdx.x >> 3;    // role 0..15
  const int tid = threadIdx.x;
  const int row_l = tid >> 2;         // 0..127
  const int q     = tid & 3;          // k-quarter
  const int g  = row_l >> 5;          // 0..3 (i,f,g,o)
  const int cl = row_l & 31;
  const int cell = (wg<<5) + cl;      // 0..511
  const int grow = (g<<9) + cell;     // global gate row

  float4 wv[32];
  {
    const float4* wp = (const float4*)(W_hh + (size_t)grow*512 + (q<<7));
    #pragma unroll
    for (int k = 0; k < 32; ++k) wv[k] = wp[k];
  }

  __shared__ float h_lds[2][4*132];   // parity double-buffer, q-blocks padded
  __shared__ float gates_lds[128];
  float c_state = 0.0f;

  for (int t = 0; t < N_TOK; ++t) {
    float xg = xp[(size_t)t*2048 + grow];   // prefetch (poll-independent)

    // poll own packed datum: tag==t means h(t)[tid] has arrived
    {
      const unsigned long long* src = hbuf + ((t & 1) << 9) + tid;
      unsigned long long v;
      do {
        v = __hip_atomic_load(src, __ATOMIC_RELAXED, __HIP_MEMORY_SCOPE_AGENT);
      } while ((unsigned)(v >> 32) != (unsigned)t);
      h_lds[t & 1][(tid >> 7)*132 + (tid & 127)] = __uint_as_float((unsigned)v);
    }
    __syncthreads();                        // barrier 1

    const float4* hv4 = (const float4*)(h_lds[t & 1] + q*132);
    float a0=0.f,a1=0.f,a2=0.f,a3=0.f;
    #pragma unroll
    for (int k = 0; k < 32; ++k) {
      float4 hv = hv4[k];
      a0 = fmaf(wv[k].x, hv.x, a0);
      a1 = fmaf(wv[k].y, hv.y, a1);
      a2 = fmaf(wv[k].z, hv.z, a2);
      a3 = fmaf(wv[k].w, hv.w, a3);
    }
    float acc = (a0+a1)+(a2+a3);
    acc += __shfl_xor(acc, 1);
    acc += __shfl_xor(acc, 2);        // all 4 q-lanes hold the full row sum
    if (q == 0) {
      float gate = acc + xg;
      gates_lds[row_l] = (g == 2) ? tanhf(gate) : 1.0f/(1.0f + expf(-gate));
    }
    __syncthreads();                        // barrier 2
    if (tid < 32) {
      float iv = gates_lds[tid];
      float fv = gates_lds[32+tid];
      float gv = gates_lds[64+tid];
      float ov = gates_lds[96+tid];
      c_state = fmaf(fv, c_state, iv*gv);
      float h = ov * tanhf(c_state);
      unsigned long long pv =
          ((unsigned long long)(unsigned)(t+1) << 32) |
          (unsigned long long)__float_as_uint(h);
      __hip_atomic_store(hbuf + (((t+1) & 1) << 9) + (wg<<5) + tid, pv,
                         __ATOMIC_RELAXED, __HIP_MEMORY_SCOPE_AGENT);
      words[(size_t)t*512 + (wg<<5) + tid] = h;  // after publish: off critical path
    }
    // no 3rd barrier (parity argument, see R7)
  }
}

// ---------------- top-50 per row (strict lower triangle), jax top_k tie semantics ----------------
__global__ __launch_bounds__(256) void topk_kernel(
    const float* __restrict__ rough,  // [2048][2048]
    float* __restrict__ tsc,          // [2048][50]
    int* __restrict__ tidx)           // [2048][50]
{
  const int i = blockIdx.x;
  const int tid = threadIdx.x;
  float v[8];
  #pragma unroll
  for (int s = 0; s < 8; ++s) {
    int j = (s<<8) + tid;
    v[s] = (j < i) ? rough[(size_t)i*N_TOK + j] : -__builtin_inff();
  }
  __shared__ float rv[4];
  __shared__ int   ri[4];
  __shared__ int   wsh;
  for (int p = 0; p < K_TOP; ++p) {
    if (p >= i) {   // padding: idx=p, finite sentinel score
      if (tid == 0) { tsc[i*K_TOP+p] = -1.0e30f; tidx[i*K_TOP+p] = p; }
      continue;
    }
    float m = -__builtin_inff(); int mi = 0x7fffffff;
    #pragma unroll
    for (int s = 0; s < 8; ++s) {
      int j = (s<<8) + tid;
      bool b = (v[s] > m);
      m = b ? v[s] : m; mi = b ? j : mi;
    }
    #pragma unroll
    for (int off = 32; off > 0; off >>= 1) {
      float m2 = __shfl_xor(m, off);
      int   i2 = __shfl_xor(mi, off);
      bool b = (m2 > m) || (m2 == m && i2 < mi);
      m = b ? m2 : m; mi = b ? i2 : mi;
    }
    if ((tid & 63) == 0) { rv[tid>>6] = m; ri[tid>>6] = mi; }
    __syncthreads();
    if (tid == 0) {
      #pragma unroll
      for (int wv = 1; wv < 4; ++wv) {
        bool b = (rv[wv] > m) || (rv[wv] == m && ri[wv] < mi);
        m = b ? rv[wv] : m; mi = b ? ri[wv] : mi;
      }
      tsc[i*K_TOP+p] = m;
      tidx[i*K_TOP+p] = mi;
      wsh = mi;
    }
    __syncthreads();
    const int widx = wsh;
    if ((widx & 255) == tid) {
      #pragma unroll
      for (int s = 0; s < 8; ++s) if ((widx >> 8) == s) v[s] = -__builtin_inff();
    }
  }
}

// ---------------- Wc -> bf16 fragment-packed layout ----------------
__global__ __launch_bounds__(256) void pack_wc(const float* __restrict__ hid_W,
                                               bf16x8* __restrict__ WcB) {
  int id = blockIdx.x*256 + threadIdx.x;   // 32768
  int c  = id & 15;
  int lg = (id >> 4) & 3;
  int ks = (id >> 6) & 15;
  int nt = id >> 10;
  const float* src = hid_W + (size_t)(nt*16 + c)*1600 + 1024 + ks*32 + lg*8;
  bf16x8 v;
  #pragma unroll
  for (int e = 0; e < 8; ++e) v[e] = (short)bfr(src[e]);
  WcB[id] = v;
}

// ---------------- pair FFNN v2: bf16 MFMA, per-i block ----------------
__global__ __launch_bounds__(256) void pair_kernel(
    const float* __restrict__ words,
    const bf16x8* __restrict__ WcB,
    const float* __restrict__ Aproj,    // [2048][512] (includes hid_b)
    const float* __restrict__ Bproj,    // [2048][512]
    const float* __restrict__ Eproj,    // [9][512]
    const float* __restrict__ outW,     // [512]
    const float* __restrict__ out_b,    // [1]
    const float* __restrict__ tsc,
    const int* __restrict__ tidx,
    float* __restrict__ out)            // [2048][51]
{
  __shared__ unsigned m_lds[64*256];    // 64 rows x 512 bf16 (64 KB)
  __shared__ int   j_sm[K_TOP];
  __shared__ int   d_sm[K_TOP];
  __shared__ float s_sm[K_TOP];
  const int i = blockIdx.x;
  const int tid = threadIdx.x;

  if (tid < K_TOP) {
    int j = tidx[i*K_TOP + tid];
    int dist = i - j; if (dist < 1) dist = 1;
    int didx;
    if (dist < 5) didx = dist - 1;
    else { int l = 31 - __clz(dist); if (l > 6) l = 6; didx = l + 2; }
    j_sm[tid] = j; d_sm[tid] = didx;
    s_sm[tid] = tsc[i*K_TOP + tid];
  }
  __syncthreads();

  {
    const int k4 = tid & 127;
    const int r0 = tid >> 7;
    const int kb = k4 >> 1, half = k4 & 1;
    const float4 a4 = *(const float4*)(words + (size_t)i*DIM + (k4<<2));
    for (int r = r0; r < K_TOP; r += 2) {
      const float4 w4 = *(const float4*)(words + (size_t)j_sm[r]*DIM + (k4<<2));
      unsigned lo = bfr(a4.x*w4.x) | (bfr(a4.y*w4.y) << 16);
      unsigned hi = bfr(a4.z*w4.z) | (bfr(a4.w*w4.w) << 16);
      unsigned off = (unsigned)r*256 + (unsigned)((kb ^ (r&7))<<2) + (half<<1);
      m_lds[off]   = lo;
      m_lds[off+1] = hi;
    }
    for (int r = K_TOP + r0; r < 64; r += 2) {
      unsigned off = (unsigned)r*256 + (unsigned)((kb ^ (r&7))<<2) + (half<<1);
      m_lds[off] = 0u; m_lds[off+1] = 0u;
    }
  }
  __syncthreads();

  const int w    = tid >> 6;
  const int lane = tid & 63;
  const int c    = lane & 15;
  const int lg   = lane >> 4;
  const int row  = (w << 4) + c;

  f32x4 acc[32];
  #pragma unroll
  for (int nt = 0; nt < 32; ++nt) acc[nt] = (f32x4){0.f,0.f,0.f,0.f};

  for (int ks = 0; ks < 16; ++ks) {
    const int kb = (ks << 2) + lg;
    bf16x8 a = *(const bf16x8*)(m_lds + (unsigned)row*256 + (unsigned)((kb ^ (row&7))<<2));
    const bf16x8* wbp = WcB + ((ks << 6) + (lg << 4) + c);
    #pragma unroll
    for (int nt = 0; nt < 32; ++nt) {
      bf16x8 b = wbp[nt << 10];
      acc[nt] = __builtin_amdgcn_mfma_f32_16x16x32_bf16(a, b, acc[nt], 0, 0, 0);
    }
  }

  const float ob = out_b[0];
  const int srow0 = (w << 4) + (lg << 2);
  const float* bpr[4];
  const float* epr[4];
  #pragma unroll
  for (int reg = 0; reg < 4; ++reg) {
    int srow = srow0 + reg;
    int jr = (srow < K_TOP) ? j_sm[srow] : 0;
    int dr = (srow < K_TOP) ? d_sm[srow] : 0;
    bpr[reg] = Bproj + (size_t)jr*DIM;
    epr[reg] = Eproj + (size_t)dr*DIM;
  }
  float p[4] = {0.f,0.f,0.f,0.f};
  #pragma unroll
  for (int nt = 0; nt < 32; ++nt) {
    int col = (nt << 4) + c;
    float ap = Aproj[(size_t)i*DIM + col];
    float ow = outW[col];
    #pragma unroll
    for (int reg = 0; reg < 4; ++reg) {
      float v = acc[nt][reg] + ap + bpr[reg][col] + epr[reg][col];
      v = (v >= 0.f) ? v : 0.01f*v;
      p[reg] = fmaf(v, ow, p[reg]);
    }
  }
  #pragma unroll
  for (int reg = 0; reg < 4; ++reg) {
    #pragma unroll
    for (int off = 1; off < 16; off <<= 1) p[reg] += __shfl_xor(p[reg], off);
  }
  if (c == 0) {
    #pragma unroll
    for (int reg = 0; reg < 4; ++reg) {
      int srow = srow0 + reg;
      if (srow < K_TOP) out[(size_t)i*51 + 1 + srow] = s_sm[srow] + p[reg] + ob;
    }
  }
  if (tid == 0) out[(size_t)i*51] = 1e-7f;
}

// ---------------- host ----------------
extern "C" void kernel_launch(void* const* d_in, const int* in_sizes, int n_in,
                              void* d_out, int out_size, void* d_ws, size_t ws_size,
                              hipStream_t stream) {
  const float* wf       = (const float*)d_in[0];
  const float* W_ih     = (const float*)d_in[1];
  const float* W_hh     = (const float*)d_in[2];
  const float* b_ih     = (const float*)d_in[3];
  const float* b_hh     = (const float*)d_in[4];
  const float* bil_W    = (const float*)d_in[5];
  const float* bil_b    = (const float*)d_in[6];
  const float* dist_emb = (const float*)d_in[7];
  const float* hid_W    = (const float*)d_in[8];
  const float* hid_b    = (const float*)d_in[9];
  const float* out_W    = (const float*)d_in[10];
  const float* out_b    = (const float*)d_in[11];
  (void)in_sizes; (void)n_in; (void)out_size; (void)ws_size;

  float* ws    = (float*)d_ws;
  float* xp    = ws;                        // 4M floats; reused as `rough`
  float* rough = ws;
  float* words = ws + 4*1024*1024;
  float* tmp   = words + N_TOK*DIM;
  float* Aproj = tmp   + N_TOK*DIM;
  float* Bproj = Aproj + N_TOK*DIM;
  float* Eproj = Bproj + N_TOK*DIM;
  bf16x8* WcB  = (bf16x8*)(Eproj + 8192);   // 512 KB
  float* tsc   = Eproj + 8192 + 131072;
  unsigned long long* hbuf = (unsigned long long*)(tsc + 102400);

  float* out_f  = (float*)d_out;
  int*   idx_out = (int*)(out_f + N_TOK*(K_TOP+1));

  dim3 blk(256);
  init_kernel<<<1, blk, 0, stream>>>(hbuf);
  // xp = wf @ W_ih^T + b_ih + b_hh      [2048 x 2048 x 512]
  gemm_nt128<<<dim3(16,16), blk, 0, stream>>>(wf, DIM, W_ih, DIM, xp, 2048,
                                              b_ih, b_hh, DIM);
  lstm_kernel<<<NWG_LSTM*8, 512, 0, stream>>>(W_hh, xp, words, hbuf);
  // tmp = words @ bil_W^T + bil_b       [2048 x 512 x 512]
  gemm_nt128<<<dim3(4,16), blk, 0, stream>>>(words, DIM, bil_W, DIM, tmp, DIM,
                                             bil_b, nullptr, DIM);
  // rough = tmp @ words^T               [2048 x 2048 x 512]
  gemm_nt128<<<dim3(16,16), blk, 0, stream>>>(tmp, DIM, words, DIM, rough, 2048,
                                              nullptr, nullptr, DIM);
  // projections of hid_W blocks         [2048 x 512 x 512]
  gemm_nt128<<<dim3(4,16), blk, 0, stream>>>(words, DIM, hid_W,       1600, Aproj, DIM,
                                             hid_b, nullptr, DIM);
  gemm_nt128<<<dim3(4,16), blk, 0, stream>>>(words, DIM, hid_W + 512, 1600, Bproj, DIM,
                                             nullptr, nullptr, DIM);
  gemm_nt<<<dim3(8,1), blk, 0, stream>>>(dist_emb, 64, hid_W + 1536, 1600, Eproj, DIM,
                                         nullptr, nullptr, 9, DIM, 64);
  pack_wc<<<128, blk, 0, stream>>>(hid_W, WcB);
  topk_kernel<<<N_TOK, blk, 0, stream>>>(rough, tsc, idx_out);
  pair_kernel<<<N_TOK, blk, 0, stream>>>(words, WcB, Aproj, Bproj, Eproj,
                                         out_W, out_b, tsc, idx_out, out_f);
}